// Round 11
// baseline (616.253 us; speedup 1.0000x reference)
//
#include <hip/hip_runtime.h>
#include <stdint.h>

#define NB 64
#define NR 1152
#define NI 64
#define NC 32
#define NO 32

typedef float float4v __attribute__((ext_vector_type(4)));

// ---------------------------------------------------------------------------
// T0: transpose x[b,r,i] -> xT[r,i,b]  (one-time, 19 MB each way, ~6 us)
// ---------------------------------------------------------------------------
__global__ __launch_bounds__(256, 4)
void k_xpose(const float* __restrict__ x, float* __restrict__ xT) {
  __shared__ float ts[64][65];
  const int r = blockIdx.x;
  const int t = threadIdx.x;
  {
    const int b = t >> 2, i0 = (t & 3) * 16;
    const float4* src = reinterpret_cast<const float4*>(x + ((size_t)b * NR + r) * NI + i0);
#pragma unroll
    for (int k = 0; k < 4; ++k) {
      const float4 v = src[k];
      ts[b][i0 + 4 * k + 0] = v.x; ts[b][i0 + 4 * k + 1] = v.y;
      ts[b][i0 + 4 * k + 2] = v.z; ts[b][i0 + 4 * k + 3] = v.w;
    }
  }
  __syncthreads();
  {
    const int i = t >> 2, b0 = (t & 3) * 16;
    float* dst = xT + ((size_t)r * NI + i) * NB + b0;
#pragma unroll
    for (int k = 0; k < 4; ++k) {
      *reinterpret_cast<float4*>(dst + 4 * k) =
          make_float4(ts[b0 + 4 * k + 0][i], ts[b0 + 4 * k + 1][i],
                      ts[b0 + 4 * k + 2][i], ts[b0 + 4 * k + 3][i]);
    }
  }
}

// ---------------------------------------------------------------------------
// K1: priors[c,b,r,o] = sum_i xT[r,i,b] * W[c,r,i,o], fp32.
// grid (NC, NR/4): c varies fastest -> all XCDs share the same hot x rows.
// Block 256 = 4 waves, wave = 1 r. Lane = bq*4+og, thread tile 4b x 8o.
// W staged per half-tile (32i x 32o = 4KB) as FOUR 1KB-coalesced wave-lines
// (round 10 bug: staged only ONE -> 3/4 garbage). Double-buffered in 32KB
// LDS, half-1 loads issued before half-0 compute. Compute reads W via
// broadcast ds_read_b128; x float4 from xT through L3.
// ---------------------------------------------------------------------------
__global__ __launch_bounds__(256, 4)
void k_priors(const float* __restrict__ xT, const float* __restrict__ W,
              float* __restrict__ P) {
  __shared__ __align__(16) float wlds[2][4][32 * 32];  // [buf][wave][i_loc*32+o] 32KB

  const int tid  = threadIdx.x;
  const int lane = tid & 63;
  const int w    = tid >> 6;
  const int c    = blockIdx.x;
  const int r    = blockIdx.y * 4 + w;
  const int og   = lane & 3;        // o = og*8 + 0..7
  const int bq   = lane >> 2;       // b = bq*4 + 0..3

  const float* Wr = W + ((size_t)c * NR + r) * (NI * NO);   // 2048 floats
  const float* xr = xT + (size_t)r * (NI * NB) + bq * 4;

  // prologue: stage half 0 (4 x 1KB wave-lines = full 4KB half-tile)
  {
    float4v s0[4];
#pragma unroll
    for (int k = 0; k < 4; ++k)
      s0[k] = __builtin_nontemporal_load(
          reinterpret_cast<const float4v*>(Wr + k * 256 + lane * 4));
#pragma unroll
    for (int k = 0; k < 4; ++k)
      *reinterpret_cast<float4v*>(&wlds[0][w][k * 256 + lane * 4]) = s0[k];
  }

  float acc[4][8];
#pragma unroll
  for (int a = 0; a < 4; ++a)
#pragma unroll
    for (int q = 0; q < 8; ++q) acc[a][q] = 0.f;

  __syncthreads();

  // issue half-1 stage loads early (in flight across half-0 compute)
  float4v s1[4];
#pragma unroll
  for (int k = 0; k < 4; ++k)
    s1[k] = __builtin_nontemporal_load(
        reinterpret_cast<const float4v*>(Wr + 1024 + k * 256 + lane * 4));

#define COMPUTE_HALF(BUF, H)                                                   \
  {                                                                            \
    const float* wb = &wlds[BUF][w][0];                                        \
    const float* xh = xr + (H) * 32 * NB;                                      \
    _Pragma("unroll")                                                          \
    for (int ig = 0; ig < 4; ++ig) {                                           \
      float4 xg[8];                                                            \
      _Pragma("unroll")                                                        \
      for (int j = 0; j < 8; ++j)                                              \
        xg[j] = *reinterpret_cast<const float4*>(xh + (ig * 8 + j) * NB);      \
      _Pragma("unroll")                                                        \
      for (int j = 0; j < 8; ++j) {                                            \
        const int i = ig * 8 + j;                                              \
        const float4 w0 = *reinterpret_cast<const float4*>(wb + i * 32 + og * 8);     \
        const float4 w1 = *reinterpret_cast<const float4*>(wb + i * 32 + og * 8 + 4); \
        const float xa[4] = {xg[j].x, xg[j].y, xg[j].z, xg[j].w};              \
        const float wv[8] = {w0.x, w0.y, w0.z, w0.w, w1.x, w1.y, w1.z, w1.w};  \
        _Pragma("unroll")                                                      \
        for (int a = 0; a < 4; ++a)                                            \
          _Pragma("unroll")                                                    \
          for (int q = 0; q < 8; ++q)                                          \
            acc[a][q] = fmaf(xa[a], wv[q], acc[a][q]);                         \
      }                                                                        \
    }                                                                          \
  }

  COMPUTE_HALF(0, 0)

  __syncthreads();
#pragma unroll
  for (int k = 0; k < 4; ++k)
    *reinterpret_cast<float4v*>(&wlds[1][w][k * 256 + lane * 4]) = s1[k];
  __syncthreads();

  COMPUTE_HALF(1, 1)
#undef COMPUTE_HALF

  // epilogue store (proven round-6/8 pattern)
#pragma unroll
  for (int a = 0; a < 4; ++a) {
    const int b = bq * 4 + a;
    float* dst = P + (((size_t)c * NB + b) * NR + r) * NO + og * 8;
    *reinterpret_cast<float4*>(dst)     = make_float4(acc[a][0], acc[a][1], acc[a][2], acc[a][3]);
    *reinterpret_cast<float4*>(dst + 4) = make_float4(acc[a][4], acc[a][5], acc[a][6], acc[a][7]);
  }
}

// ---------------------------------------------------------------------------
// K2: full 3-iteration routing for one (c,b). block 1024 (16 waves).
// 8 lanes per route-row (sl = o-slice of 4); P slice in registers p[9],
// read from global exactly once, coalesced 1 KB per wave instruction.
// ---------------------------------------------------------------------------
__device__ __forceinline__ void merge4(float& m, float& Z, float4& T,
                                       float m2, float Z2, const float4& T2) {
  const float mn = fmaxf(m, m2);
  const float a1 = __expf(m - mn), a2 = __expf(m2 - mn);
  Z   = Z * a1 + Z2 * a2;
  T.x = T.x * a1 + T2.x * a2;
  T.y = T.y * a1 + T2.y * a2;
  T.z = T.z * a1 + T2.z * a2;
  T.w = T.w * a1 + T2.w * a2;
  m = mn;
}

__global__ __launch_bounds__(1024, 1)
void k_route(const float* __restrict__ P, float* __restrict__ out) {
  __shared__ float red_s[16][8][8];  // [wave][slice][m,Z,T0..3,pad2]
  __shared__ float u_s[NO];

  const int tid  = threadIdx.x;
  const int lane = tid & 63;
  const int wave = tid >> 6;
  const int sl   = tid & 7;   // o-slice: o = sl*4 + 0..3
  const int grp  = tid >> 3;  // row group 0..127; rows r = grp + 128*j
  const int b    = blockIdx.x;
  const int c    = blockIdx.y;
  const float* Pb = P + ((size_t)c * NB + b) * ((size_t)NR * NO);

  float4 p[9];
#pragma unroll
  for (int j = 0; j < 9; ++j)
    p[j] = *reinterpret_cast<const float4*>(Pb + (size_t)(grp + 128 * j) * NO + sl * 4);

  // ---- iteration 0: uniform softmax -> S0 = mean_r p ----
  {
    float4 T = p[0];
#pragma unroll
    for (int j = 1; j < 9; ++j) {
      T.x += p[j].x; T.y += p[j].y; T.z += p[j].z; T.w += p[j].w;
    }
#pragma unroll
    for (int off = 8; off <= 32; off <<= 1) {
      T.x += __shfl_xor(T.x, off); T.y += __shfl_xor(T.y, off);
      T.z += __shfl_xor(T.z, off); T.w += __shfl_xor(T.w, off);
    }
    if (lane < 8) {
      red_s[wave][sl][2] = T.x; red_s[wave][sl][3] = T.y;
      red_s[wave][sl][4] = T.z; red_s[wave][sl][5] = T.w;
    }
  }
  __syncthreads();
  if (tid < 8) {
    float4 S = make_float4(0.f, 0.f, 0.f, 0.f);
#pragma unroll
    for (int ww = 0; ww < 16; ++ww) {
      S.x += red_s[ww][tid][2]; S.y += red_s[ww][tid][3];
      S.z += red_s[ww][tid][4]; S.w += red_s[ww][tid][5];
    }
    S.x *= (1.f / NR); S.y *= (1.f / NR); S.z *= (1.f / NR); S.w *= (1.f / NR);
    float n2 = S.x * S.x + S.y * S.y + S.z * S.z + S.w * S.w;
    n2 += __shfl_xor(n2, 1); n2 += __shfl_xor(n2, 2); n2 += __shfl_xor(n2, 4);
    const float scale = n2 / ((1.f + n2) * sqrtf(n2));
    u_s[tid * 4 + 0] = S.x * scale; u_s[tid * 4 + 1] = S.y * scale;
    u_s[tid * 4 + 2] = S.z * scale; u_s[tid * 4 + 3] = S.w * scale;
  }
  __syncthreads();

  float4 u = *reinterpret_cast<const float4*>(&u_s[sl * 4]);
  float l1[9];

  for (int it = 1; it <= 2; ++it) {
    float m = -3.0e38f, Z = 0.f;
    float4 T = make_float4(0.f, 0.f, 0.f, 0.f);
#pragma unroll
    for (int j = 0; j < 9; ++j) {
      float d = p[j].x * u.x + p[j].y * u.y + p[j].z * u.z + p[j].w * u.w;
      d += __shfl_xor(d, 1); d += __shfl_xor(d, 2); d += __shfl_xor(d, 4);
      float l;
      if (it == 1) { l1[j] = d; l = d; }
      else         { l = l1[j] + d; }
      const float mn = fmaxf(m, l);
      const float a = __expf(m - mn);
      const float e = __expf(l - mn);
      Z   = Z * a + e;
      T.x = T.x * a + e * p[j].x; T.y = T.y * a + e * p[j].y;
      T.z = T.z * a + e * p[j].z; T.w = T.w * a + e * p[j].w;
      m = mn;
    }
#pragma unroll
    for (int off = 8; off <= 32; off <<= 1) {
      const float m2 = __shfl_xor(m, off);
      const float Z2 = __shfl_xor(Z, off);
      float4 T2;
      T2.x = __shfl_xor(T.x, off); T2.y = __shfl_xor(T.y, off);
      T2.z = __shfl_xor(T.z, off); T2.w = __shfl_xor(T.w, off);
      merge4(m, Z, T, m2, Z2, T2);
    }
    if (lane < 8) {
      red_s[wave][sl][0] = m;   red_s[wave][sl][1] = Z;
      red_s[wave][sl][2] = T.x; red_s[wave][sl][3] = T.y;
      red_s[wave][sl][4] = T.z; red_s[wave][sl][5] = T.w;
    }
    __syncthreads();
    if (tid < 8) {
      float mm = red_s[0][tid][0], ZZ = red_s[0][tid][1];
      float4 TT = make_float4(red_s[0][tid][2], red_s[0][tid][3],
                              red_s[0][tid][4], red_s[0][tid][5]);
#pragma unroll
      for (int ww = 1; ww < 16; ++ww) {
        const float4 T2 = make_float4(red_s[ww][tid][2], red_s[ww][tid][3],
                                      red_s[ww][tid][4], red_s[ww][tid][5]);
        merge4(mm, ZZ, TT, red_s[ww][tid][0], red_s[ww][tid][1], T2);
      }
      const float inv = 1.f / ZZ;
      float4 S = make_float4(TT.x * inv, TT.y * inv, TT.z * inv, TT.w * inv);
      float n2 = S.x * S.x + S.y * S.y + S.z * S.z + S.w * S.w;
      n2 += __shfl_xor(n2, 1); n2 += __shfl_xor(n2, 2); n2 += __shfl_xor(n2, 4);
      const float scale = n2 / ((1.f + n2) * sqrtf(n2));
      if (it == 1) {
        u_s[tid * 4 + 0] = S.x * scale; u_s[tid * 4 + 1] = S.y * scale;
        u_s[tid * 4 + 2] = S.z * scale; u_s[tid * 4 + 3] = S.w * scale;
      } else {
        *reinterpret_cast<float4*>(out + ((size_t)b * NC + c) * NO + tid * 4) =
            make_float4(S.x * scale, S.y * scale, S.z * scale, S.w * scale);
      }
    }
    __syncthreads();
    if (it == 1) u = *reinterpret_cast<const float4*>(&u_s[sl * 4]);
  }
}

extern "C" void kernel_launch(void* const* d_in, const int* in_sizes, int n_in,
                              void* d_out, int out_size, void* d_ws, size_t ws_size,
                              hipStream_t stream) {
  const float* x = (const float*)d_in[0];
  // d_in[1] (cond) is unused by the reference computation
  const float* W = (const float*)d_in[2];
  float* out = (float*)d_out;

  float* xT = (float*)d_ws;                       // 18.9 MB
  const size_t xT_floats = (size_t)NR * NI * NB;
  float* P = xT + xT_floats;                      // 302 MB

  k_xpose<<<NR, 256, 0, stream>>>(x, xT);
  k_priors<<<dim3(NC, NR / 4), 256, 0, stream>>>(xT, W, P);
  k_route<<<dim3(NB, NC), 1024, 0, stream>>>(P, out);
}

// Round 12
// 316.612 us; speedup vs baseline: 1.9464x; 1.9464x over previous
//
#include <hip/hip_runtime.h>
#include <stdint.h>

#define NB 64
#define NR 1152
#define NI 64
#define NC 32
#define NO 32

typedef float float4v __attribute__((ext_vector_type(4)));

// ---------------------------------------------------------------------------
// T0: transpose x[b,r,i] -> xT[r,i,b]  (one-time, 19 MB each way, ~6 us)
// ---------------------------------------------------------------------------
__global__ __launch_bounds__(256, 4)
void k_xpose(const float* __restrict__ x, float* __restrict__ xT) {
  __shared__ float ts[64][65];
  const int r = blockIdx.x;
  const int t = threadIdx.x;
  {
    const int b = t >> 2, i0 = (t & 3) * 16;
    const float4* src = reinterpret_cast<const float4*>(x + ((size_t)b * NR + r) * NI + i0);
#pragma unroll
    for (int k = 0; k < 4; ++k) {
      const float4 v = src[k];
      ts[b][i0 + 4 * k + 0] = v.x; ts[b][i0 + 4 * k + 1] = v.y;
      ts[b][i0 + 4 * k + 2] = v.z; ts[b][i0 + 4 * k + 3] = v.w;
    }
  }
  __syncthreads();
  {
    const int i = t >> 2, b0 = (t & 3) * 16;
    float* dst = xT + ((size_t)r * NI + i) * NB + b0;
#pragma unroll
    for (int k = 0; k < 4; ++k) {
      *reinterpret_cast<float4*>(dst + 4 * k) =
          make_float4(ts[b0 + 4 * k + 0][i], ts[b0 + 4 * k + 1][i],
                      ts[b0 + 4 * k + 2][i], ts[b0 + 4 * k + 3][i]);
    }
  }
}

// ---------------------------------------------------------------------------
// K1: priors[c,b,r,o] = sum_i xT[r,i,b] * W[c,r,i,o], fp32.
// grid (NC, NR/4), c fastest (XCDs share hot x rows). Block 256 = 4 waves,
// wave = 1 r, ZERO barriers (wave-private LDS slice, same-wave lgkmcnt).
// Lane: bh = lane>>3 (b = bh*8+a), og = lane&7 (o = og*4+q).
// Thread tile 8b x 4o -> acc[8][4] = 32 VGPR (allocator-safe shape).
// Per i: 1 ds_read_b128 W (12 LDS-cyc) vs 64 SIMD-cyc FMA -> 75% LDS headroom.
// W staged once per r: 8 NT 1KB-coalesced wave-lines into 8KB LDS slice.
// No macros, no reg-array batching, no held prefetch regs (~60 VGPR peak).
// ---------------------------------------------------------------------------
__global__ __launch_bounds__(256, 4)
void k_priors(const float* __restrict__ xT, const float* __restrict__ W,
              float* __restrict__ P) {
  __shared__ __align__(16) float wlds[4][NI * NO];  // 4 x 8KB, wave-private

  const int tid  = threadIdx.x;
  const int lane = tid & 63;
  const int w    = tid >> 6;
  const int c    = blockIdx.x;
  const int r    = blockIdx.y * 4 + w;
  const int og   = lane & 7;        // o = og*4 + 0..3
  const int bh   = lane >> 3;       // b = bh*8 + 0..7

  const float* Wr = W + ((size_t)c * NR + r) * (NI * NO);   // 2048 floats
  float* wb = &wlds[w][0];

  // stage whole 8KB W tile: 8 x (1KB-coalesced NT load -> LDS write)
#pragma unroll
  for (int k = 0; k < 8; ++k) {
    const float4v s = __builtin_nontemporal_load(
        reinterpret_cast<const float4v*>(Wr + k * 256 + lane * 4));
    *reinterpret_cast<float4v*>(wb + k * 256 + lane * 4) = s;
  }

  float acc[8][4];
#pragma unroll
  for (int a = 0; a < 8; ++a)
#pragma unroll
    for (int q = 0; q < 4; ++q) acc[a][q] = 0.f;

  const float* xrow = xT + (size_t)r * (NI * NB) + bh * 8;

#pragma unroll 8
  for (int i = 0; i < NI; ++i) {
    const float4 xa = *reinterpret_cast<const float4*>(xrow + i * NB);
    const float4 xb = *reinterpret_cast<const float4*>(xrow + i * NB + 4);
    const float4 wv = *reinterpret_cast<const float4*>(wb + i * NO + og * 4);
    const float xv[8] = {xa.x, xa.y, xa.z, xa.w, xb.x, xb.y, xb.z, xb.w};
    const float wq[4] = {wv.x, wv.y, wv.z, wv.w};
#pragma unroll
    for (int a = 0; a < 8; ++a)
#pragma unroll
      for (int q = 0; q < 4; ++q)
        acc[a][q] = fmaf(xv[a], wq[q], acc[a][q]);
  }

  // store: per a, lanes (og 0..7) write 8 consecutive 16B = 128B per b-row
#pragma unroll
  for (int a = 0; a < 8; ++a) {
    const int b = bh * 8 + a;
    float* dst = P + (((size_t)c * NB + b) * NR + r) * NO + og * 4;
    *reinterpret_cast<float4*>(dst) =
        make_float4(acc[a][0], acc[a][1], acc[a][2], acc[a][3]);
  }
}

// ---------------------------------------------------------------------------
// K2: full 3-iteration routing for one (c,b). block 1024 (16 waves).
// 8 lanes per route-row (sl = o-slice of 4); P slice in registers p[9],
// read from global exactly once, coalesced 1 KB per wave instruction.
// ---------------------------------------------------------------------------
__device__ __forceinline__ void merge4(float& m, float& Z, float4& T,
                                       float m2, float Z2, const float4& T2) {
  const float mn = fmaxf(m, m2);
  const float a1 = __expf(m - mn), a2 = __expf(m2 - mn);
  Z   = Z * a1 + Z2 * a2;
  T.x = T.x * a1 + T2.x * a2;
  T.y = T.y * a1 + T2.y * a2;
  T.z = T.z * a1 + T2.z * a2;
  T.w = T.w * a1 + T2.w * a2;
  m = mn;
}

__global__ __launch_bounds__(1024, 1)
void k_route(const float* __restrict__ P, float* __restrict__ out) {
  __shared__ float red_s[16][8][8];  // [wave][slice][m,Z,T0..3,pad2]
  __shared__ float u_s[NO];

  const int tid  = threadIdx.x;
  const int lane = tid & 63;
  const int wave = tid >> 6;
  const int sl   = tid & 7;   // o-slice: o = sl*4 + 0..3
  const int grp  = tid >> 3;  // row group 0..127; rows r = grp + 128*j
  const int b    = blockIdx.x;
  const int c    = blockIdx.y;
  const float* Pb = P + ((size_t)c * NB + b) * ((size_t)NR * NO);

  float4 p[9];
#pragma unroll
  for (int j = 0; j < 9; ++j)
    p[j] = *reinterpret_cast<const float4*>(Pb + (size_t)(grp + 128 * j) * NO + sl * 4);

  // ---- iteration 0: uniform softmax -> S0 = mean_r p ----
  {
    float4 T = p[0];
#pragma unroll
    for (int j = 1; j < 9; ++j) {
      T.x += p[j].x; T.y += p[j].y; T.z += p[j].z; T.w += p[j].w;
    }
#pragma unroll
    for (int off = 8; off <= 32; off <<= 1) {
      T.x += __shfl_xor(T.x, off); T.y += __shfl_xor(T.y, off);
      T.z += __shfl_xor(T.z, off); T.w += __shfl_xor(T.w, off);
    }
    if (lane < 8) {
      red_s[wave][sl][2] = T.x; red_s[wave][sl][3] = T.y;
      red_s[wave][sl][4] = T.z; red_s[wave][sl][5] = T.w;
    }
  }
  __syncthreads();
  if (tid < 8) {
    float4 S = make_float4(0.f, 0.f, 0.f, 0.f);
#pragma unroll
    for (int ww = 0; ww < 16; ++ww) {
      S.x += red_s[ww][tid][2]; S.y += red_s[ww][tid][3];
      S.z += red_s[ww][tid][4]; S.w += red_s[ww][tid][5];
    }
    S.x *= (1.f / NR); S.y *= (1.f / NR); S.z *= (1.f / NR); S.w *= (1.f / NR);
    float n2 = S.x * S.x + S.y * S.y + S.z * S.z + S.w * S.w;
    n2 += __shfl_xor(n2, 1); n2 += __shfl_xor(n2, 2); n2 += __shfl_xor(n2, 4);
    const float scale = n2 / ((1.f + n2) * sqrtf(n2));
    u_s[tid * 4 + 0] = S.x * scale; u_s[tid * 4 + 1] = S.y * scale;
    u_s[tid * 4 + 2] = S.z * scale; u_s[tid * 4 + 3] = S.w * scale;
  }
  __syncthreads();

  float4 u = *reinterpret_cast<const float4*>(&u_s[sl * 4]);
  float l1[9];

  for (int it = 1; it <= 2; ++it) {
    float m = -3.0e38f, Z = 0.f;
    float4 T = make_float4(0.f, 0.f, 0.f, 0.f);
#pragma unroll
    for (int j = 0; j < 9; ++j) {
      float d = p[j].x * u.x + p[j].y * u.y + p[j].z * u.z + p[j].w * u.w;
      d += __shfl_xor(d, 1); d += __shfl_xor(d, 2); d += __shfl_xor(d, 4);
      float l;
      if (it == 1) { l1[j] = d; l = d; }
      else         { l = l1[j] + d; }
      const float mn = fmaxf(m, l);
      const float a = __expf(m - mn);
      const float e = __expf(l - mn);
      Z   = Z * a + e;
      T.x = T.x * a + e * p[j].x; T.y = T.y * a + e * p[j].y;
      T.z = T.z * a + e * p[j].z; T.w = T.w * a + e * p[j].w;
      m = mn;
    }
#pragma unroll
    for (int off = 8; off <= 32; off <<= 1) {
      const float m2 = __shfl_xor(m, off);
      const float Z2 = __shfl_xor(Z, off);
      float4 T2;
      T2.x = __shfl_xor(T.x, off); T2.y = __shfl_xor(T.y, off);
      T2.z = __shfl_xor(T.z, off); T2.w = __shfl_xor(T.w, off);
      merge4(m, Z, T, m2, Z2, T2);
    }
    if (lane < 8) {
      red_s[wave][sl][0] = m;   red_s[wave][sl][1] = Z;
      red_s[wave][sl][2] = T.x; red_s[wave][sl][3] = T.y;
      red_s[wave][sl][4] = T.z; red_s[wave][sl][5] = T.w;
    }
    __syncthreads();
    if (tid < 8) {
      float mm = red_s[0][tid][0], ZZ = red_s[0][tid][1];
      float4 TT = make_float4(red_s[0][tid][2], red_s[0][tid][3],
                              red_s[0][tid][4], red_s[0][tid][5]);
#pragma unroll
      for (int ww = 1; ww < 16; ++ww) {
        const float4 T2 = make_float4(red_s[ww][tid][2], red_s[ww][tid][3],
                                      red_s[ww][tid][4], red_s[ww][tid][5]);
        merge4(mm, ZZ, TT, red_s[ww][tid][0], red_s[ww][tid][1], T2);
      }
      const float inv = 1.f / ZZ;
      float4 S = make_float4(TT.x * inv, TT.y * inv, TT.z * inv, TT.w * inv);
      float n2 = S.x * S.x + S.y * S.y + S.z * S.z + S.w * S.w;
      n2 += __shfl_xor(n2, 1); n2 += __shfl_xor(n2, 2); n2 += __shfl_xor(n2, 4);
      const float scale = n2 / ((1.f + n2) * sqrtf(n2));
      if (it == 1) {
        u_s[tid * 4 + 0] = S.x * scale; u_s[tid * 4 + 1] = S.y * scale;
        u_s[tid * 4 + 2] = S.z * scale; u_s[tid * 4 + 3] = S.w * scale;
      } else {
        *reinterpret_cast<float4*>(out + ((size_t)b * NC + c) * NO + tid * 4) =
            make_float4(S.x * scale, S.y * scale, S.z * scale, S.w * scale);
      }
    }
    __syncthreads();
    if (it == 1) u = *reinterpret_cast<const float4*>(&u_s[sl * 4]);
  }
}

extern "C" void kernel_launch(void* const* d_in, const int* in_sizes, int n_in,
                              void* d_out, int out_size, void* d_ws, size_t ws_size,
                              hipStream_t stream) {
  const float* x = (const float*)d_in[0];
  // d_in[1] (cond) is unused by the reference computation
  const float* W = (const float*)d_in[2];
  float* out = (float*)d_out;

  float* xT = (float*)d_ws;                       // 18.9 MB
  const size_t xT_floats = (size_t)NR * NI * NB;
  float* P = xT + xT_floats;                      // 302 MB

  k_xpose<<<NR, 256, 0, stream>>>(x, xT);
  k_priors<<<dim3(NC, NR / 4), 256, 0, stream>>>(xT, W, P);
  k_route<<<dim3(NB, NC), 1024, 0, stream>>>(P, out);
}